// Round 1
// baseline (1523.253 us; speedup 1.0000x reference)
//
#include <hip/hip_runtime.h>

// ---------------------------------------------------------------------------
// GCN: out = Conv2( relu(Conv1( relu(Conv0(x)) )) )
// Conv(h) = D^-1/2 (A+I) D^-1/2 (h W) + b   ==  ((D^-1/2 (A+I) D^-1/2) h) W + b
// We aggregate BEFORE the GEMM for layer 0 (128 < 256) and AFTER for layer 2
// (128 < 256), minimizing per-edge gather width.
// CSR (grouped by destination) is rebuilt every call from edge_index.
// ---------------------------------------------------------------------------

template<int VEC> struct VecT;
template<> struct VecT<4> { using T = float4; };
template<> struct VecT<2> { using T = float2; };

__global__ __launch_bounds__(256) void count_edges(const int* __restrict__ col,
                                                   int E, int* __restrict__ cnt) {
    int e = blockIdx.x * 256 + threadIdx.x;
    if (e < E) atomicAdd(&cnt[col[e]], 1);
}

// Single-block scan over N counts -> exclusive offsets, cursor copy, dinv.
__global__ __launch_bounds__(1024) void scan_offsets(const int* __restrict__ cnt, int Nn,
                                                     int* __restrict__ offs,
                                                     int* __restrict__ cursor,
                                                     float* __restrict__ dinv) {
    __shared__ int sums[1024];
    int t = threadIdx.x;
    int chunk = (Nn + 1023) >> 10;
    int b = t * chunk;
    int e = min(b + chunk, Nn);
    int s = 0;
    for (int i = b; i < e; ++i) s += cnt[i];
    sums[t] = s;
    __syncthreads();
    // Hillis-Steele inclusive scan over 1024 partials
    for (int off = 1; off < 1024; off <<= 1) {
        int v = 0;
        if (t >= off) v = sums[t - off];
        __syncthreads();
        sums[t] += v;
        __syncthreads();
    }
    int run = (t > 0) ? sums[t - 1] : 0;
    for (int i = b; i < e; ++i) {
        offs[i] = run;
        cursor[i] = run;
        run += cnt[i];
        dinv[i] = rsqrtf((float)(cnt[i] + 1));  // +1 = self loop
    }
    if (t == 0) offs[Nn] = sums[1023];
}

__global__ __launch_bounds__(256) void fill_csr(const int* __restrict__ row,
                                                const int* __restrict__ col, int E,
                                                int* __restrict__ cursor,
                                                int* __restrict__ esrc) {
    int e = blockIdx.x * 256 + threadIdx.x;
    if (e < E) {
        int pos = atomicAdd(&cursor[col[e]], 1);
        esrc[pos] = row[e];
    }
}

// One wave (64 lanes) per destination node; lane owns VEC consecutive floats.
// out[c] = dinv[c] * ( dinv[c]*h[c] + sum_{s in N(c)} dinv[s]*h[s] ) [+ bias]
template<int VEC, bool BIAS>
__global__ __launch_bounds__(256) void aggregate(const float* __restrict__ h,
                                                 const float* __restrict__ dinv,
                                                 const int* __restrict__ offs,
                                                 const int* __restrict__ esrc,
                                                 const float* __restrict__ bias,
                                                 float* __restrict__ out, int Nn) {
    const int D = VEC * 64;
    int node = (int)((blockIdx.x * 256u + threadIdx.x) >> 6);
    if (node >= Nn) return;
    int lane = threadIdx.x & 63;
    using T = typename VecT<VEC>::T;

    float dc = dinv[node];
    const float* hr = h + (size_t)node * D + lane * VEC;
    float acc[VEC];
    {
        T v = *(const T*)hr;
        const float* vp = (const float*)&v;
#pragma unroll
        for (int j = 0; j < VEC; ++j) acc[j] = dc * vp[j];
    }
    int e0 = offs[node], e1 = offs[node + 1];
    for (int k = e0; k < e1; ++k) {
        int s = esrc[k];
        float ds = dinv[s];
        T u = *(const T*)(h + (size_t)s * D + lane * VEC);
        const float* up = (const float*)&u;
#pragma unroll
        for (int j = 0; j < VEC; ++j) acc[j] = fmaf(ds, up[j], acc[j]);
    }
    T w;
    float* wp = (float*)&w;
#pragma unroll
    for (int j = 0; j < VEC; ++j) {
        float val = acc[j] * dc;
        if (BIAS) val += bias[lane * VEC + j];
        wp[j] = val;
    }
    *(T*)(out + (size_t)node * D + lane * VEC) = w;
}

// C[Nrows,Dout] = A[Nrows,K] @ W[K,Dout] (+bias) (+relu). fp32 vector ALU.
// 64x64 tile per 256-thread block, 4x4 per thread, BK=16.
template<bool RELU, bool BIAS>
__global__ __launch_bounds__(256) void gemm64x64(const float* __restrict__ A,
                                                 const float* __restrict__ W,
                                                 const float* __restrict__ bias,
                                                 float* __restrict__ C,
                                                 int Nrows, int K, int Dout) {
    __shared__ float As[16][64];  // transposed A tile: As[k][m]
    __shared__ float Bs[16][64];  // Bs[k][n]
    int t = threadIdx.x;
    int tx = t & 15, ty = t >> 4;
    int m0 = blockIdx.y << 6, n0 = blockIdx.x << 6;
    float acc[4][4] = {};

    int arow = t >> 2, aseg = t & 3;       // A tile: 64 rows x 4 float4 segs
    int brow = t >> 4, bcol = (t & 15) << 2;  // B tile: 16 rows x 16 float4 segs
    int agr = m0 + arow;
    const bool aval = agr < Nrows;
    const float* arp = A + (size_t)agr * K + (aseg << 2);

    for (int k0 = 0; k0 < K; k0 += 16) {
        float4 av = make_float4(0.f, 0.f, 0.f, 0.f);
        if (aval) av = *(const float4*)(arp + k0);
        As[(aseg << 2) + 0][arow] = av.x;
        As[(aseg << 2) + 1][arow] = av.y;
        As[(aseg << 2) + 2][arow] = av.z;
        As[(aseg << 2) + 3][arow] = av.w;
        *(float4*)&Bs[brow][bcol] =
            *(const float4*)&W[(size_t)(k0 + brow) * Dout + n0 + bcol];
        __syncthreads();
#pragma unroll
        for (int k = 0; k < 16; ++k) {
            float4 a = *(const float4*)&As[k][ty << 2];
            float4 b = *(const float4*)&Bs[k][tx << 2];
            const float* ap = (const float*)&a;
            const float* bp = (const float*)&b;
#pragma unroll
            for (int i = 0; i < 4; ++i)
#pragma unroll
                for (int j = 0; j < 4; ++j)
                    acc[i][j] = fmaf(ap[i], bp[j], acc[i][j]);
        }
        __syncthreads();
    }

    float4 bv = make_float4(0.f, 0.f, 0.f, 0.f);
    if (BIAS) bv = *(const float4*)&bias[n0 + (tx << 2)];
    const float* bvp = (const float*)&bv;
#pragma unroll
    for (int i = 0; i < 4; ++i) {
        int gr = m0 + (ty << 2) + i;
        if (gr < Nrows) {
            float4 o;
            float* op = (float*)&o;
#pragma unroll
            for (int j = 0; j < 4; ++j) {
                float val = acc[i][j];
                if (BIAS) val += bvp[j];
                if (RELU) val = fmaxf(val, 0.f);
                op[j] = val;
            }
            *(float4*)&C[(size_t)gr * Dout + n0 + (tx << 2)] = o;
        }
    }
}

extern "C" void kernel_launch(void* const* d_in, const int* in_sizes, int n_in,
                              void* d_out, int out_size, void* d_ws, size_t ws_size,
                              hipStream_t stream) {
    const float* x  = (const float*)d_in[0];
    const int*   ei = (const int*)d_in[1];
    const float* W0 = (const float*)d_in[4];
    const float* b0 = (const float*)d_in[5];
    const float* W1 = (const float*)d_in[6];
    const float* b1 = (const float*)d_in[7];
    const float* W2 = (const float*)d_in[8];
    const float* b2 = (const float*)d_in[9];

    const int N = in_sizes[0] / 128;
    const int E = in_sizes[1] / 2;
    const int* row = ei;       // edge_index[0] = sources
    const int* col = ei + E;   // edge_index[1] = destinations

    // Workspace carve (256B aligned)
    char* w = (char*)d_ws;
    auto carve = [&](size_t bytes) {
        void* p = (void*)w;
        w += (bytes + 255) & ~(size_t)255;
        return p;
    };
    int*   cnt    = (int*)carve((size_t)N * 4);
    int*   offs   = (int*)carve((size_t)(N + 1) * 4);
    int*   cursor = (int*)carve((size_t)N * 4);
    int*   esrc   = (int*)carve((size_t)E * 4);
    float* dinv   = (float*)carve((size_t)N * 4);
    float* bufA   = (float*)carve((size_t)N * 256 * 4);
    float* bufB   = (float*)carve((size_t)N * 256 * 4);

    // --- CSR build ---
    hipMemsetAsync(cnt, 0, (size_t)N * 4, stream);
    count_edges<<<(E + 255) / 256, 256, 0, stream>>>(col, E, cnt);
    scan_offsets<<<1, 1024, 0, stream>>>(cnt, N, offs, cursor, dinv);
    fill_csr<<<(E + 255) / 256, 256, 0, stream>>>(row, col, E, cursor, esrc);

    const int aggBlocks = (N + 3) / 4;  // 4 waves/block, 1 node/wave

    // --- Layer 0: ag = Â x (D=128), h1 = relu(ag @ W0 + b0) ---
    aggregate<2, false><<<aggBlocks, 256, 0, stream>>>(x, dinv, offs, esrc, nullptr, bufA, N);
    {
        dim3 g(256 / 64, (N + 63) / 64);
        gemm64x64<true, true><<<g, 256, 0, stream>>>(bufA, W0, b0, bufB, N, 128, 256);
    }
    // --- Layer 1: ag = Â h1 (D=256), h2 = relu(ag @ W1 + b1) ---
    aggregate<4, false><<<aggBlocks, 256, 0, stream>>>(bufB, dinv, offs, esrc, nullptr, bufA, N);
    {
        dim3 g(256 / 64, (N + 63) / 64);
        gemm64x64<true, true><<<g, 256, 0, stream>>>(bufA, W1, b1, bufB, N, 256, 256);
    }
    // --- Layer 2: hw = h2 @ W2 (no bias), out = Â hw + b2 (D=128) ---
    {
        dim3 g(128 / 64, (N + 63) / 64);
        gemm64x64<false, false><<<g, 256, 0, stream>>>(bufB, W2, nullptr, bufA, N, 256, 128);
    }
    aggregate<2, true><<<aggBlocks, 256, 0, stream>>>(bufA, dinv, offs, esrc, b2, (float*)d_out, N);
}

// Round 2
// 1224.078 us; speedup vs baseline: 1.2444x; 1.2444x over previous
//
#include <hip/hip_runtime.h>

// ---------------------------------------------------------------------------
// GCN: out = Conv2( relu(Conv1( relu(Conv0(x)) )) )
// Conv(h) = Â (h W) + b == (Â h) W + b,  Â = D^-1/2 (A+I) D^-1/2
// Aggregate BEFORE GEMM for layer 0 (D=128<256), AFTER for layer 2.
// CSR-by-destination rebuilt every call (count -> 3-kernel scan -> fill).
// ---------------------------------------------------------------------------

template<int VEC> struct VecT;
template<> struct VecT<4> { using T = float4; };
template<> struct VecT<2> { using T = float2; };

__global__ __launch_bounds__(256) void count_edges(const int* __restrict__ col,
                                                   int E, int* __restrict__ cnt) {
    int e = blockIdx.x * 256 + threadIdx.x;
    if (e < E) atomicAdd(&cnt[col[e]], 1);
}

// --- multi-block exclusive scan over cnt[N] (chunk = 2048/block) ---
__global__ __launch_bounds__(256) void scan_reduce(const int* __restrict__ cnt, int Nn,
                                                   int* __restrict__ blockSums) {
    __shared__ int s[256];
    int t = threadIdx.x;
    int base = blockIdx.x * 2048 + t * 8;
    int v = 0;
#pragma unroll
    for (int j = 0; j < 8; ++j) {
        int i = base + j;
        if (i < Nn) v += cnt[i];
    }
    s[t] = v;
    __syncthreads();
    for (int off = 128; off > 0; off >>= 1) {
        if (t < off) s[t] += s[t + off];
        __syncthreads();
    }
    if (t == 0) blockSums[blockIdx.x] = s[0];
}

__global__ void scan_partials(int* __restrict__ blockSums, int nb,
                              int* __restrict__ offs, int Nn) {
    if (threadIdx.x == 0 && blockIdx.x == 0) {
        int run = 0;
        for (int i = 0; i < nb; ++i) {
            int v = blockSums[i];
            blockSums[i] = run;
            run += v;
        }
        offs[Nn] = run;
    }
}

__global__ __launch_bounds__(256) void scan_finish(const int* __restrict__ cnt, int Nn,
                                                   const int* __restrict__ blockSums,
                                                   int* __restrict__ offs,
                                                   int* __restrict__ cursor,
                                                   float* __restrict__ dinv) {
    __shared__ int s[256];
    int t = threadIdx.x;
    int base = blockIdx.x * 2048 + t * 8;
    int c[8];
    int sum = 0;
#pragma unroll
    for (int j = 0; j < 8; ++j) {
        int i = base + j;
        c[j] = (i < Nn) ? cnt[i] : 0;
        sum += c[j];
    }
    s[t] = sum;
    __syncthreads();
    for (int off = 1; off < 256; off <<= 1) {
        int v = (t >= off) ? s[t - off] : 0;
        __syncthreads();
        s[t] += v;
        __syncthreads();
    }
    int run = ((t > 0) ? s[t - 1] : 0) + blockSums[blockIdx.x];
#pragma unroll
    for (int j = 0; j < 8; ++j) {
        int i = base + j;
        if (i < Nn) {
            offs[i] = run;
            cursor[i] = run;
            dinv[i] = rsqrtf((float)(c[j] + 1));  // +1 = self loop
            run += c[j];
        }
    }
}

__global__ __launch_bounds__(256) void fill_csr(const int* __restrict__ row,
                                                const int* __restrict__ col, int E,
                                                int* __restrict__ cursor,
                                                int* __restrict__ esrc) {
    int e = blockIdx.x * 256 + threadIdx.x;
    if (e < E) {
        int pos = atomicAdd(&cursor[col[e]], 1);
        esrc[pos] = row[e];
    }
}

// One wave (64 lanes) per destination node; lane owns VEC consecutive floats.
// out[c] = dinv[c] * ( dinv[c]*h[c] + sum_{s in N(c)} dinv[s]*h[s] ) [+ bias]
template<int VEC, bool BIAS>
__global__ __launch_bounds__(256) void aggregate(const float* __restrict__ h,
                                                 const float* __restrict__ dinv,
                                                 const int* __restrict__ offs,
                                                 const int* __restrict__ esrc,
                                                 const float* __restrict__ bias,
                                                 float* __restrict__ out, int Nn) {
    const int D = VEC * 64;
    int node = (int)((blockIdx.x * 256u + threadIdx.x) >> 6);
    if (node >= Nn) return;
    int lane = threadIdx.x & 63;
    using T = typename VecT<VEC>::T;

    float dc = dinv[node];
    const float* hr = h + (size_t)node * D + lane * VEC;
    float acc[VEC];
    {
        T v = *(const T*)hr;
        const float* vp = (const float*)&v;
#pragma unroll
        for (int j = 0; j < VEC; ++j) acc[j] = dc * vp[j];
    }
    int e0 = offs[node], e1 = offs[node + 1];
    for (int k = e0; k < e1; ++k) {
        int s = esrc[k];
        float ds = dinv[s];
        T u = *(const T*)(h + (size_t)s * D + lane * VEC);
        const float* up = (const float*)&u;
#pragma unroll
        for (int j = 0; j < VEC; ++j) acc[j] = fmaf(ds, up[j], acc[j]);
    }
    T w;
    float* wp = (float*)&w;
#pragma unroll
    for (int j = 0; j < VEC; ++j) {
        float val = acc[j] * dc;
        if (BIAS) val += bias[lane * VEC + j];
        wp[j] = val;
    }
    *(T*)(out + (size_t)node * D + lane * VEC) = w;
}

// C[Nrows,Dout] = A[Nrows,K] @ W[K,Dout] (+bias) (+relu). fp32 vector ALU.
// 128x128 tile / 256 threads, 8x8 per thread (cols split tx*4 and 64+tx*4 so
// all LDS traffic is <=2-way bank aliased, i.e. free), BK=16.
template<bool RELU, bool BIAS>
__global__ __launch_bounds__(256) void gemm128x128(const float* __restrict__ A,
                                                   const float* __restrict__ W,
                                                   const float* __restrict__ bias,
                                                   float* __restrict__ C,
                                                   int Nrows, int K, int Dout) {
    __shared__ float As[16][128];  // As[k][m]
    __shared__ float Bs[16][128];  // Bs[k][n]
    int t = threadIdx.x;
    int tx = t & 15, ty = t >> 4;
    int m0 = blockIdx.y << 7, n0 = blockIdx.x << 7;
    float acc[8][8] = {};

    // A staging: thread -> (row = t>>1, k-halve = (t&1)*8), two float4s
    int arow = t >> 1;
    int akoff = (t & 1) << 3;
    int agr = m0 + arow;
    const bool aval = agr < Nrows;
    const float* ap0 = A + (size_t)agr * K + akoff;
    // B staging: thread -> (krow = t>>4, cols tx*4 and 64+tx*4)
    int brow = t >> 4;
    int bcol = (t & 15) << 2;

    for (int k0 = 0; k0 < K; k0 += 16) {
        float4 av0 = make_float4(0.f, 0.f, 0.f, 0.f), av1 = av0;
        if (aval) {
            av0 = *(const float4*)(ap0 + k0);
            av1 = *(const float4*)(ap0 + k0 + 4);
        }
        const float* wp = W + (size_t)(k0 + brow) * Dout + n0;
        float4 bv0 = *(const float4*)(wp + bcol);
        float4 bv1 = *(const float4*)(wp + 64 + bcol);
        __syncthreads();  // previous tile fully consumed
        As[akoff + 0][arow] = av0.x;
        As[akoff + 1][arow] = av0.y;
        As[akoff + 2][arow] = av0.z;
        As[akoff + 3][arow] = av0.w;
        As[akoff + 4][arow] = av1.x;
        As[akoff + 5][arow] = av1.y;
        As[akoff + 6][arow] = av1.z;
        As[akoff + 7][arow] = av1.w;
        *(float4*)&Bs[brow][bcol] = bv0;
        *(float4*)&Bs[brow][64 + bcol] = bv1;
        __syncthreads();
#pragma unroll
        for (int k = 0; k < 16; ++k) {
            float4 a0 = *(const float4*)&As[k][ty << 3];
            float4 a1 = *(const float4*)&As[k][(ty << 3) + 4];
            float4 b0 = *(const float4*)&Bs[k][tx << 2];
            float4 b1 = *(const float4*)&Bs[k][64 + (tx << 2)];
            const float* a0p = (const float*)&a0;
            const float* a1p = (const float*)&a1;
            const float* b0p = (const float*)&b0;
            const float* b1p = (const float*)&b1;
#pragma unroll
            for (int i = 0; i < 4; ++i)
#pragma unroll
                for (int j = 0; j < 4; ++j) {
                    acc[i][j]         = fmaf(a0p[i], b0p[j], acc[i][j]);
                    acc[i][j + 4]     = fmaf(a0p[i], b1p[j], acc[i][j + 4]);
                    acc[i + 4][j]     = fmaf(a1p[i], b0p[j], acc[i + 4][j]);
                    acc[i + 4][j + 4] = fmaf(a1p[i], b1p[j], acc[i + 4][j + 4]);
                }
        }
    }

    float4 bias0 = make_float4(0.f, 0.f, 0.f, 0.f), bias1 = bias0;
    if (BIAS) {
        bias0 = *(const float4*)&bias[n0 + (tx << 2)];
        bias1 = *(const float4*)&bias[n0 + 64 + (tx << 2)];
    }
    const float* b0p = (const float*)&bias0;
    const float* b1p = (const float*)&bias1;
#pragma unroll
    for (int i = 0; i < 8; ++i) {
        int gr = m0 + (ty << 3) + i;
        if (gr < Nrows) {
            float4 o0, o1;
            float* o0p = (float*)&o0;
            float* o1p = (float*)&o1;
#pragma unroll
            for (int j = 0; j < 4; ++j) {
                float v0 = acc[i][j] + (BIAS ? b0p[j] : 0.f);
                float v1 = acc[i][j + 4] + (BIAS ? b1p[j] : 0.f);
                if (RELU) { v0 = fmaxf(v0, 0.f); v1 = fmaxf(v1, 0.f); }
                o0p[j] = v0;
                o1p[j] = v1;
            }
            float* cp = C + (size_t)gr * Dout + n0;
            *(float4*)(cp + (tx << 2)) = o0;
            *(float4*)(cp + 64 + (tx << 2)) = o1;
        }
    }
}

extern "C" void kernel_launch(void* const* d_in, const int* in_sizes, int n_in,
                              void* d_out, int out_size, void* d_ws, size_t ws_size,
                              hipStream_t stream) {
    const float* x  = (const float*)d_in[0];
    const int*   ei = (const int*)d_in[1];
    const float* W0 = (const float*)d_in[4];
    const float* b0 = (const float*)d_in[5];
    const float* W1 = (const float*)d_in[6];
    const float* b1 = (const float*)d_in[7];
    const float* W2 = (const float*)d_in[8];
    const float* b2 = (const float*)d_in[9];

    const int N = in_sizes[0] / 128;
    const int E = in_sizes[1] / 2;
    const int* row = ei;       // edge_index[0] = sources
    const int* col = ei + E;   // edge_index[1] = destinations

    char* w = (char*)d_ws;
    auto carve = [&](size_t bytes) {
        void* p = (void*)w;
        w += (bytes + 255) & ~(size_t)255;
        return p;
    };
    const int NB = (N + 2047) / 2048;  // scan blocks
    int*   cnt    = (int*)carve((size_t)N * 4);
    int*   offs   = (int*)carve((size_t)(N + 1) * 4);
    int*   cursor = (int*)carve((size_t)N * 4);
    int*   esrc   = (int*)carve((size_t)E * 4);
    float* dinv   = (float*)carve((size_t)N * 4);
    int*   bsums  = (int*)carve((size_t)NB * 4);
    float* bufA   = (float*)carve((size_t)N * 256 * 4);
    float* bufB   = (float*)carve((size_t)N * 256 * 4);

    // --- CSR build ---
    hipMemsetAsync(cnt, 0, (size_t)N * 4, stream);
    count_edges<<<(E + 255) / 256, 256, 0, stream>>>(col, E, cnt);
    scan_reduce<<<NB, 256, 0, stream>>>(cnt, N, bsums);
    scan_partials<<<1, 64, 0, stream>>>(bsums, NB, offs, N);
    scan_finish<<<NB, 256, 0, stream>>>(cnt, N, bsums, offs, cursor, dinv);
    fill_csr<<<(E + 255) / 256, 256, 0, stream>>>(row, col, E, cursor, esrc);

    const int aggBlocks = (N + 3) / 4;  // 4 waves/block, 1 node/wave

    // --- Layer 0: ag = Â x (D=128), h1 = relu(ag @ W0 + b0) ---
    aggregate<2, false><<<aggBlocks, 256, 0, stream>>>(x, dinv, offs, esrc, nullptr, bufA, N);
    {
        dim3 g(256 / 128, (N + 127) / 128);
        gemm128x128<true, true><<<g, 256, 0, stream>>>(bufA, W0, b0, bufB, N, 128, 256);
    }
    // --- Layer 1: ag = Â h1 (D=256), h2 = relu(ag @ W1 + b1) ---
    aggregate<4, false><<<aggBlocks, 256, 0, stream>>>(bufB, dinv, offs, esrc, nullptr, bufA, N);
    {
        dim3 g(256 / 128, (N + 127) / 128);
        gemm128x128<true, true><<<g, 256, 0, stream>>>(bufA, W1, b1, bufB, N, 256, 256);
    }
    // --- Layer 2: hw = h2 @ W2 (no bias), out = Â hw + b2 (D=128) ---
    {
        dim3 g(128 / 128, (N + 127) / 128);
        gemm128x128<false, false><<<g, 256, 0, stream>>>(bufB, W2, nullptr, bufA, N, 256, 128);
    }
    aggregate<2, true><<<aggBlocks, 256, 0, stream>>>(bufA, dinv, offs, esrc, b2, (float*)d_out, N);
}

// Round 3
// 769.914 us; speedup vs baseline: 1.9785x; 1.5899x over previous
//
#include <hip/hip_runtime.h>

// ---------------------------------------------------------------------------
// GCN, bf16 internal pipeline:
//   convert x->bf16; agg0 = Â x (bf16 out); h1 = relu(agg0@W0+b0) [MFMA bf16]
//   agg1 = Â h1; h2 = relu(agg1@W1+b1); hw = h2@W2; out = Â hw + b2 (fp32)
// Aggregation gathers bf16 rows (half the random-gather HBM traffic);
// GEMMs use v_mfma_f32_16x16x32_bf16 with fragment-major LDS staged via
// global_load_lds width=16 (lane-contiguous -> conflict-free ds_read_b128).
// W is pre-transposed to Wt[Dout][K] bf16 so B-fragment 16B chunks are
// contiguous in global memory.
// ---------------------------------------------------------------------------

typedef __attribute__((ext_vector_type(8))) short bf16x8;
typedef __attribute__((ext_vector_type(4))) float f32x4;

__device__ __forceinline__ float bf_lo(unsigned u) {
    union { unsigned i; float f; } x; x.i = u << 16; return x.f;
}
__device__ __forceinline__ float bf_hi(unsigned u) {
    union { unsigned i; float f; } x; x.i = u & 0xFFFF0000u; return x.f;
}
__device__ __forceinline__ unsigned short f2bf(float f) {  // RNE
    union { float f; unsigned i; } x; x.f = f;
    unsigned r = x.i + 0x7FFFu + ((x.i >> 16) & 1u);
    return (unsigned short)(r >> 16);
}

// ----------------------------- CSR build -----------------------------------

__global__ __launch_bounds__(256) void count_edges(const int* __restrict__ col,
                                                   int E, int* __restrict__ cnt) {
    int e = blockIdx.x * 256 + threadIdx.x;
    if (e < E) atomicAdd(&cnt[col[e]], 1);
}

__global__ __launch_bounds__(256) void scan_reduce(const int* __restrict__ cnt, int Nn,
                                                   int* __restrict__ blockSums) {
    __shared__ int s[256];
    int t = threadIdx.x;
    int base = blockIdx.x * 2048 + t * 8;
    int v = 0;
#pragma unroll
    for (int j = 0; j < 8; ++j) {
        int i = base + j;
        if (i < Nn) v += cnt[i];
    }
    s[t] = v;
    __syncthreads();
    for (int off = 128; off > 0; off >>= 1) {
        if (t < off) s[t] += s[t + off];
        __syncthreads();
    }
    if (t == 0) blockSums[blockIdx.x] = s[0];
}

__global__ void scan_partials(int* __restrict__ blockSums, int nb,
                              int* __restrict__ offs, int Nn) {
    if (threadIdx.x == 0 && blockIdx.x == 0) {
        int run = 0;
        for (int i = 0; i < nb; ++i) {
            int v = blockSums[i];
            blockSums[i] = run;
            run += v;
        }
        offs[Nn] = run;
    }
}

__global__ __launch_bounds__(256) void scan_finish(const int* __restrict__ cnt, int Nn,
                                                   const int* __restrict__ blockSums,
                                                   int* __restrict__ offs,
                                                   int* __restrict__ cursor,
                                                   float* __restrict__ dinv) {
    __shared__ int s[256];
    int t = threadIdx.x;
    int base = blockIdx.x * 2048 + t * 8;
    int c[8];
    int sum = 0;
#pragma unroll
    for (int j = 0; j < 8; ++j) {
        int i = base + j;
        c[j] = (i < Nn) ? cnt[i] : 0;
        sum += c[j];
    }
    s[t] = sum;
    __syncthreads();
    for (int off = 1; off < 256; off <<= 1) {
        int v = (t >= off) ? s[t - off] : 0;
        __syncthreads();
        s[t] += v;
        __syncthreads();
    }
    int run = ((t > 0) ? s[t - 1] : 0) + blockSums[blockIdx.x];
#pragma unroll
    for (int j = 0; j < 8; ++j) {
        int i = base + j;
        if (i < Nn) {
            offs[i] = run;
            cursor[i] = run;
            dinv[i] = rsqrtf((float)(c[j] + 1));  // +1 self loop
            run += c[j];
        }
    }
}

__global__ __launch_bounds__(256) void fill_csr(const int* __restrict__ row,
                                                const int* __restrict__ col, int E,
                                                int* __restrict__ cursor,
                                                int* __restrict__ esrc) {
    int e = blockIdx.x * 256 + threadIdx.x;
    if (e < E) {
        int pos = atomicAdd(&cursor[col[e]], 1);
        esrc[pos] = row[e];
    }
}

// ----------------------------- converters ----------------------------------

__global__ __launch_bounds__(256) void f32_to_bf16(const float4* __restrict__ src,
                                                   uint2* __restrict__ dst, int n4) {
    int i = blockIdx.x * 256 + threadIdx.x;
    if (i < n4) {
        float4 v = src[i];
        uint2 o;
        o.x = (unsigned)f2bf(v.x) | ((unsigned)f2bf(v.y) << 16);
        o.y = (unsigned)f2bf(v.z) | ((unsigned)f2bf(v.w) << 16);
        dst[i] = o;
    }
}

// Wt[n*K + k] = bf16(W[k*Dout + n])
__global__ __launch_bounds__(256) void conv_transpose_w(const float* __restrict__ W,
                                                        unsigned short* __restrict__ Wt,
                                                        int K, int Dout) {
    int i = blockIdx.x * 256 + threadIdx.x;
    if (i < K * Dout) {
        int n = i / K, k = i - n * K;
        Wt[i] = f2bf(W[(size_t)k * Dout + n]);
    }
}

// ----------------------------- aggregation ---------------------------------
// One wave per dest node. hb rows are bf16, packed 2/uint; UPL uints per lane.
// D = 128*UPL. out[c] = dinv[c]*( dinv[c]*h[c] + sum_s dinv[s]*h[s] ) [+bias]
template<int UPL, bool OUTBF, bool BIAS>
__global__ __launch_bounds__(256) void aggregate_bf(const unsigned* __restrict__ hb,
                                                    const float* __restrict__ dinv,
                                                    const int* __restrict__ offs,
                                                    const int* __restrict__ esrc,
                                                    const float* __restrict__ bias,
                                                    void* __restrict__ out, int Nn) {
    int node = (int)((blockIdx.x * 256u + threadIdx.x) >> 6);
    if (node >= Nn) return;
    int lane = threadIdx.x & 63;
    const int RW = 64 * UPL;  // uints per row
    float dc = dinv[node];
    float acc[2 * UPL];
    {
        const unsigned* p = hb + (size_t)node * RW + lane * UPL;
        unsigned u[UPL];
#pragma unroll
        for (int q = 0; q < UPL; ++q) u[q] = p[q];
#pragma unroll
        for (int q = 0; q < UPL; ++q) {
            acc[2 * q]     = dc * bf_lo(u[q]);
            acc[2 * q + 1] = dc * bf_hi(u[q]);
        }
    }
    int e0 = offs[node], e1 = offs[node + 1];
    int k = e0;
    for (; k + 2 <= e1; k += 2) {  // 2-way unrolled for MLP
        int s0 = esrc[k], s1 = esrc[k + 1];
        float d0 = dinv[s0], d1 = dinv[s1];
        const unsigned* p0 = hb + (size_t)s0 * RW + lane * UPL;
        const unsigned* p1 = hb + (size_t)s1 * RW + lane * UPL;
        unsigned a0[UPL], a1[UPL];
#pragma unroll
        for (int q = 0; q < UPL; ++q) { a0[q] = p0[q]; a1[q] = p1[q]; }
#pragma unroll
        for (int q = 0; q < UPL; ++q) {
            acc[2 * q]     = fmaf(d0, bf_lo(a0[q]), acc[2 * q]);
            acc[2 * q + 1] = fmaf(d0, bf_hi(a0[q]), acc[2 * q + 1]);
            acc[2 * q]     = fmaf(d1, bf_lo(a1[q]), acc[2 * q]);
            acc[2 * q + 1] = fmaf(d1, bf_hi(a1[q]), acc[2 * q + 1]);
        }
    }
    if (k < e1) {
        int s0 = esrc[k];
        float d0 = dinv[s0];
        const unsigned* p0 = hb + (size_t)s0 * RW + lane * UPL;
#pragma unroll
        for (int q = 0; q < UPL; ++q) {
            unsigned u = p0[q];
            acc[2 * q]     = fmaf(d0, bf_lo(u), acc[2 * q]);
            acc[2 * q + 1] = fmaf(d0, bf_hi(u), acc[2 * q + 1]);
        }
    }
    if (OUTBF) {
        unsigned* o = (unsigned*)out + (size_t)node * RW + lane * UPL;
#pragma unroll
        for (int q = 0; q < UPL; ++q) {
            float v0 = acc[2 * q] * dc;
            float v1 = acc[2 * q + 1] * dc;
            o[q] = (unsigned)f2bf(v0) | ((unsigned)f2bf(v1) << 16);
        }
    } else {
        float* o = (float*)out + (size_t)node * (RW * 2) + lane * (UPL * 2);
#pragma unroll
        for (int q = 0; q < UPL; ++q) {
            float b0v = BIAS ? bias[(lane * UPL + q) * 2 + 0] : 0.f;
            float b1v = BIAS ? bias[(lane * UPL + q) * 2 + 1] : 0.f;
            o[2 * q]     = acc[2 * q] * dc + b0v;
            o[2 * q + 1] = acc[2 * q + 1] * dc + b1v;
        }
    }
}

// ----------------------------- MFMA GEMM -----------------------------------
// C[Nrows,Dout] = A[Nrows,K]@W[K,Dout] (+bias)(+relu), A/Wt bf16, C bf16/f32.
// Bt = W^T as [Dout][K]. 128x128 tile / 4 waves (2x2 wave grid, 64x64 each).
// LDS is fragment-major: tile t -> 64 lanes x 16B, so staging is
// global_load_lds (wave-uniform base + lane*16) and frag reads are
// lane-contiguous ds_read_b128 (conflict-free).
// Frag layouts (m89/m91-verified): A: m=lane&15, k=(lane>>4)*8+j
//                                  B: n=lane&15, k=(lane>>4)*8+j
//                                  C: col=lane&15, row=(lane>>4)*4+reg
template<int K, bool RELU, bool BIAS, bool OUTBF>
__global__ __launch_bounds__(256) void gemm_mfma(const unsigned short* __restrict__ A,
                                                 const unsigned short* __restrict__ Bt,
                                                 const float* __restrict__ bias,
                                                 void* __restrict__ C,
                                                 int Nrows, int Dout) {
    __shared__ __align__(16) unsigned short As[8 * 64 * 8];  // 8KB
    __shared__ __align__(16) unsigned short Bs[8 * 64 * 8];  // 8KB
    int t = threadIdx.x;
    int w = t >> 6, lane = t & 63;
    int lrow = lane & 15, lkq = lane >> 4;
    int wr = w >> 1, wc = w & 1;
    int m0 = blockIdx.y << 7;
    int n0 = blockIdx.x << 7;

    int at0 = 2 * w, at1 = 2 * w + 1;
    int ar0 = min(m0 + at0 * 16 + lrow, Nrows - 1);
    int ar1 = min(m0 + at1 * 16 + lrow, Nrows - 1);
    const unsigned short* agp0 = A + (size_t)ar0 * K + lkq * 8;
    const unsigned short* agp1 = A + (size_t)ar1 * K + lkq * 8;
    const unsigned short* bgp0 = Bt + (size_t)(n0 + at0 * 16 + lrow) * K + lkq * 8;
    const unsigned short* bgp1 = Bt + (size_t)(n0 + at1 * 16 + lrow) * K + lkq * 8;
    unsigned short* asl0 = &As[at0 * 512];
    unsigned short* asl1 = &As[at1 * 512];
    unsigned short* bsl0 = &Bs[at0 * 512];
    unsigned short* bsl1 = &Bs[at1 * 512];

    f32x4 acc[4][4];
#pragma unroll
    for (int i = 0; i < 4; ++i)
#pragma unroll
        for (int j = 0; j < 4; ++j) acc[i][j] = (f32x4){0.f, 0.f, 0.f, 0.f};

    for (int k0 = 0; k0 < K; k0 += 32) {
        __syncthreads();  // previous step's frags fully consumed
        __builtin_amdgcn_global_load_lds(
            (const __attribute__((address_space(1))) void*)(agp0 + k0),
            (__attribute__((address_space(3))) void*)asl0, 16, 0, 0);
        __builtin_amdgcn_global_load_lds(
            (const __attribute__((address_space(1))) void*)(agp1 + k0),
            (__attribute__((address_space(3))) void*)asl1, 16, 0, 0);
        __builtin_amdgcn_global_load_lds(
            (const __attribute__((address_space(1))) void*)(bgp0 + k0),
            (__attribute__((address_space(3))) void*)bsl0, 16, 0, 0);
        __builtin_amdgcn_global_load_lds(
            (const __attribute__((address_space(1))) void*)(bgp1 + k0),
            (__attribute__((address_space(3))) void*)bsl1, 16, 0, 0);
        __syncthreads();  // drains vmcnt -> staged data visible
        bf16x8 af[4], bfr[4];
#pragma unroll
        for (int i = 0; i < 4; ++i)
            af[i] = *(const bf16x8*)&As[(((wr * 4 + i) * 64) + lane) * 8];
#pragma unroll
        for (int j = 0; j < 4; ++j)
            bfr[j] = *(const bf16x8*)&Bs[(((wc * 4 + j) * 64) + lane) * 8];
#pragma unroll
        for (int i = 0; i < 4; ++i)
#pragma unroll
            for (int j = 0; j < 4; ++j)
                acc[i][j] = __builtin_amdgcn_mfma_f32_16x16x32_bf16(
                    af[i], bfr[j], acc[i][j], 0, 0, 0);
    }

#pragma unroll
    for (int j = 0; j < 4; ++j) {
        int col = n0 + ((wc * 4 + j) << 4) + lrow;
        float bj = BIAS ? bias[col] : 0.f;
#pragma unroll
        for (int i = 0; i < 4; ++i) {
            int rb = m0 + ((wr * 4 + i) << 4) + (lkq << 2);
            f32x4 c = acc[i][j];
#pragma unroll
            for (int r = 0; r < 4; ++r) {
                int row = rb + r;
                if (row < Nrows) {
                    float v = c[r] + bj;
                    if (RELU) v = fmaxf(v, 0.f);
                    if (OUTBF)
                        ((unsigned short*)C)[(size_t)row * Dout + col] = f2bf(v);
                    else
                        ((float*)C)[(size_t)row * Dout + col] = v;
                }
            }
        }
    }
}

// ----------------------------- launch --------------------------------------

extern "C" void kernel_launch(void* const* d_in, const int* in_sizes, int n_in,
                              void* d_out, int out_size, void* d_ws, size_t ws_size,
                              hipStream_t stream) {
    const float* x  = (const float*)d_in[0];
    const int*   ei = (const int*)d_in[1];
    const float* W0 = (const float*)d_in[4];
    const float* b0 = (const float*)d_in[5];
    const float* W1 = (const float*)d_in[6];
    const float* b1 = (const float*)d_in[7];
    const float* W2 = (const float*)d_in[8];
    const float* b2 = (const float*)d_in[9];

    const int N = in_sizes[0] / 128;
    const int E = in_sizes[1] / 2;
    const int* row = ei;       // sources
    const int* col = ei + E;   // destinations

    char* wp = (char*)d_ws;
    auto carve = [&](size_t bytes) {
        void* p = (void*)wp;
        wp += (bytes + 255) & ~(size_t)255;
        return p;
    };
    const int NB = (N + 2047) / 2048;
    int*   cnt    = (int*)carve((size_t)N * 4);
    int*   offs   = (int*)carve((size_t)(N + 1) * 4);
    int*   cursor = (int*)carve((size_t)N * 4);
    int*   esrc   = (int*)carve((size_t)E * 4);
    float* dinv   = (float*)carve((size_t)N * 4);
    int*   bsums  = (int*)carve((size_t)NB * 4);
    unsigned short* Wt0 = (unsigned short*)carve((size_t)256 * 128 * 2);
    unsigned short* Wt1 = (unsigned short*)carve((size_t)256 * 256 * 2);
    unsigned short* Wt2 = (unsigned short*)carve((size_t)128 * 256 * 2);
    // regionX (N*256 bf16): xb | agg0b, later reused whole as h2b
    unsigned short* regX = (unsigned short*)carve((size_t)N * 256 * 2);
    unsigned short* xb    = regX;                       // N*128 bf16
    unsigned short* agg0b = regX + (size_t)N * 128;     // N*128 bf16
    unsigned short* h2b   = regX;                       // N*256 bf16 (after agg0b dead)
    // region h1 (N*256 bf16): h1b, later reused as hwb
    unsigned short* h1b = (unsigned short*)carve((size_t)N * 256 * 2);
    unsigned short* hwb = h1b;                          // N*128 bf16 (after h1b dead)
    unsigned short* agg1b = (unsigned short*)carve((size_t)N * 256 * 2);

    // --- CSR build ---
    hipMemsetAsync(cnt, 0, (size_t)N * 4, stream);
    count_edges<<<(E + 255) / 256, 256, 0, stream>>>(col, E, cnt);
    scan_reduce<<<NB, 256, 0, stream>>>(cnt, N, bsums);
    scan_partials<<<1, 64, 0, stream>>>(bsums, NB, offs, N);
    scan_finish<<<NB, 256, 0, stream>>>(cnt, N, bsums, offs, cursor, dinv);
    fill_csr<<<(E + 255) / 256, 256, 0, stream>>>(row, col, E, cursor, esrc);

    // --- converts (independent of CSR) ---
    {
        int n4 = N * 128 / 4;
        f32_to_bf16<<<(n4 + 255) / 256, 256, 0, stream>>>((const float4*)x, (uint2*)xb, n4);
        conv_transpose_w<<<(128 * 256 + 255) / 256, 256, 0, stream>>>(W0, Wt0, 128, 256);
        conv_transpose_w<<<(256 * 256 + 255) / 256, 256, 0, stream>>>(W1, Wt1, 256, 256);
        conv_transpose_w<<<(256 * 128 + 255) / 256, 256, 0, stream>>>(W2, Wt2, 256, 128);
    }

    const int aggBlocks = (N + 3) / 4;  // 1 node/wave, 4 waves/block
    dim3 g2col(2, (N + 127) / 128);
    dim3 g1col(1, (N + 127) / 128);

    // L0: agg0 = Â xb ; h1 = relu(agg0 @ W0 + b0)
    aggregate_bf<1, true, false><<<aggBlocks, 256, 0, stream>>>(
        (const unsigned*)xb, dinv, offs, esrc, nullptr, agg0b, N);
    gemm_mfma<128, true, true, true><<<g2col, 256, 0, stream>>>(agg0b, Wt0, b0, h1b, N, 256);
    // L1: agg1 = Â h1 ; h2 = relu(agg1 @ W1 + b1)
    aggregate_bf<2, true, false><<<aggBlocks, 256, 0, stream>>>(
        (const unsigned*)h1b, dinv, offs, esrc, nullptr, agg1b, N);
    gemm_mfma<256, true, true, true><<<g2col, 256, 0, stream>>>(agg1b, Wt1, b1, h2b, N, 256);
    // L2: hw = h2 @ W2 ; out = Â hw + b2 (fp32)
    gemm_mfma<256, false, false, true><<<g1col, 256, 0, stream>>>(h2b, Wt2, nullptr, hwb, N, 128);
    aggregate_bf<1, false, true><<<aggBlocks, 256, 0, stream>>>(
        (const unsigned*)hwb, dinv, offs, esrc, b2, d_out, N);
}